// Round 2
// baseline (634.419 us; speedup 1.0000x reference)
//
#include <hip/hip_runtime.h>
#include <hip/hip_bf16.h>

// ---------------------------------------------------------------------------
// GraphSAGE 2-layer: out = sage2( relu(sage1(x)) )
// sage(h, Wl, bl, Wr) = mean_agg(h) @ Wl + bl + h @ Wr
// Linearity: mean_agg(h) @ W == mean_agg(h @ W) -> transform first, then
// aggregate; layer-2 aggregation moves 32 floats/edge, not 128.
// NOTE: harness passes ALL integer inputs as int32 (edge_index int64 in the
// reference becomes const int* here). Round-1 crash was casting it to i64.
// ---------------------------------------------------------------------------

#define FDIM 128
#define CDIM 32

// ---- CSR build ------------------------------------------------------------

__global__ void deg_kernel(const int* __restrict__ dst, int* __restrict__ deg,
                           int E, int n) {
    int e = blockIdx.x * 256 + threadIdx.x;
    if (e < E) {
        int d = dst[e];
        if (d >= 0 && d < n) atomicAdd(&deg[d], 1);
    }
}

// single block, 256 threads: chunked exclusive scan of deg -> rowptr, plus inv_deg
__global__ void scan_kernel(const int* __restrict__ deg, int* __restrict__ rowptr,
                            float* __restrict__ inv_deg, int n) {
    __shared__ int sums[256];
    int t = threadIdx.x;
    int chunk = (n + 255) / 256;
    int lo = t * chunk;
    int hi = lo + chunk; if (hi > n) hi = n;
    int s = 0;
    for (int i = lo; i < hi; i++) s += deg[i];
    sums[t] = s;
    __syncthreads();
    if (t == 0) {
        int run = 0;
        for (int i = 0; i < 256; i++) { int v = sums[i]; sums[i] = run; run += v; }
    }
    __syncthreads();
    int run = sums[t];
    for (int i = lo; i < hi; i++) {
        rowptr[i] = run;
        int d = deg[i];
        run += d;
        inv_deg[i] = 1.0f / (float)(d > 0 ? d : 1);
    }
}

__global__ void fill_kernel(const int* __restrict__ src, const int* __restrict__ dst,
                            const int* __restrict__ rowptr, int* __restrict__ cursor,
                            int* __restrict__ nbr, int E, int n) {
    int e = blockIdx.x * 256 + threadIdx.x;
    if (e < E) {
        int s = src[e];
        int d = dst[e];
        if (d >= 0 && d < n) {
            int p = atomicAdd(&cursor[d], 1);
            nbr[rowptr[d] + p] = s;
        }
    }
}

// ---- GEMM1: y = x @ W1l, r = x @ W1r  ([N,128] @ [128,128] x2) ------------
// block: 256 threads, 64 rows. K staged in slices of 32.
// thread (tx=t&15, ty=t>>4) computes 4 rows x 8 cols for each of Wl, Wr.

__global__ __launch_bounds__(256) void gemm1_kernel(
        const float* __restrict__ x, const float* __restrict__ Wl,
        const float* __restrict__ Wr, float* __restrict__ y,
        float* __restrict__ r, int n) {
    __shared__ float xs[64 * 36];      // stride 36: 16B-aligned, conflict-light
    __shared__ float wls[32 * 128];
    __shared__ float wrs[32 * 128];

    const int t  = threadIdx.x;
    const int tx = t & 15;
    const int ty = t >> 4;
    const int row0 = blockIdx.x * 64;

    float accl[4][8];
    float accr[4][8];
#pragma unroll
    for (int i = 0; i < 4; i++)
#pragma unroll
        for (int j = 0; j < 8; j++) { accl[i][j] = 0.f; accr[i][j] = 0.f; }

    for (int k0 = 0; k0 < 128; k0 += 32) {
        __syncthreads();
        // stage x slice: 64x32 floats = 512 float4, 2 per thread
#pragma unroll
        for (int i = 0; i < 2; i++) {
            int q   = t + i * 256;
            int row = q >> 3;
            int kq  = (q & 7) << 2;
            float4 v = make_float4(0.f, 0.f, 0.f, 0.f);
            int gr = row0 + row;
            if (gr < n) v = *(const float4*)(x + (size_t)gr * FDIM + k0 + kq);
            *(float4*)(xs + row * 36 + kq) = v;
        }
        // stage W slices: 32x128 floats = 1024 float4 each, 4 per thread
#pragma unroll
        for (int i = 0; i < 4; i++) {
            int q    = t + i * 256;
            int wrow = q >> 5;
            int wc   = (q & 31) << 2;
            *(float4*)(wls + wrow * 128 + wc) = *(const float4*)(Wl + (k0 + wrow) * 128 + wc);
            *(float4*)(wrs + wrow * 128 + wc) = *(const float4*)(Wr + (k0 + wrow) * 128 + wc);
        }
        __syncthreads();

#pragma unroll
        for (int kk = 0; kk < 32; kk++) {
            float a[4];
#pragma unroll
            for (int i = 0; i < 4; i++) a[i] = xs[(ty * 4 + i) * 36 + kk];
            float4 bl0 = *(const float4*)(wls + kk * 128 + tx * 8);
            float4 bl1 = *(const float4*)(wls + kk * 128 + tx * 8 + 4);
            float4 br0 = *(const float4*)(wrs + kk * 128 + tx * 8);
            float4 br1 = *(const float4*)(wrs + kk * 128 + tx * 8 + 4);
            float bl[8] = {bl0.x, bl0.y, bl0.z, bl0.w, bl1.x, bl1.y, bl1.z, bl1.w};
            float br[8] = {br0.x, br0.y, br0.z, br0.w, br1.x, br1.y, br1.z, br1.w};
#pragma unroll
            for (int i = 0; i < 4; i++)
#pragma unroll
                for (int j = 0; j < 8; j++) {
                    accl[i][j] = fmaf(a[i], bl[j], accl[i][j]);
                    accr[i][j] = fmaf(a[i], br[j], accr[i][j]);
                }
        }
    }

#pragma unroll
    for (int i = 0; i < 4; i++) {
        int gr = row0 + ty * 4 + i;
        if (gr < n) {
            float* yp = y + (size_t)gr * FDIM + tx * 8;
            float* rp = r + (size_t)gr * FDIM + tx * 8;
            *(float4*)(yp)     = make_float4(accl[i][0], accl[i][1], accl[i][2], accl[i][3]);
            *(float4*)(yp + 4) = make_float4(accl[i][4], accl[i][5], accl[i][6], accl[i][7]);
            *(float4*)(rp)     = make_float4(accr[i][0], accr[i][1], accr[i][2], accr[i][3]);
            *(float4*)(rp + 4) = make_float4(accr[i][4], accr[i][5], accr[i][6], accr[i][7]);
        }
    }
}

// ---- combine1: h = relu(inv_deg * sum_j y1[j] + r1 + b1), in place over r1 -

__global__ __launch_bounds__(128) void combine1_kernel(
        const float* __restrict__ y1, const int* __restrict__ rowptr,
        const int* __restrict__ deg, const int* __restrict__ nbr,
        const float* __restrict__ inv_deg, const float* __restrict__ b1,
        float* __restrict__ h /* == r1, in-place */, int n) {
    int i = blockIdx.x;
    int f = threadIdx.x;
    int start = rowptr[i];
    int d     = deg[i];
    float s = 0.f;
    for (int e = 0; e < d; e++) {
        int j = nbr[start + e];
        s += y1[(size_t)j * FDIM + f];
    }
    float v = s * inv_deg[i] + h[(size_t)i * FDIM + f] + b1[f];
    h[(size_t)i * FDIM + f] = v > 0.f ? v : 0.f;
}

// ---- GEMM2: z = h @ W2l, r = h @ W2r  ([N,128] @ [128,32] x2) -------------
// block: 256 threads, 128 rows. W fully LDS-resident.
// thread (tx=t&7, ty=t>>3) computes 4 rows x 4 cols for each matrix.

__global__ __launch_bounds__(256) void gemm2_kernel(
        const float* __restrict__ h, const float* __restrict__ Wl,
        const float* __restrict__ Wr, float* __restrict__ z,
        float* __restrict__ r, int n) {
    __shared__ float xs[128 * 36];
    __shared__ float wls[128 * 32];
    __shared__ float wrs[128 * 32];

    const int t  = threadIdx.x;
    const int tx = t & 7;
    const int ty = t >> 3;
    const int row0 = blockIdx.x * 128;

    // stage W fully: 128x32 = 4096 floats = 1024 float4 each, 4 per thread
#pragma unroll
    for (int i = 0; i < 4; i++) {
        int q    = t + i * 256;
        int wrow = q >> 3;
        int wc   = (q & 7) << 2;
        *(float4*)(wls + wrow * 32 + wc) = *(const float4*)(Wl + wrow * 32 + wc);
        *(float4*)(wrs + wrow * 32 + wc) = *(const float4*)(Wr + wrow * 32 + wc);
    }

    float accl[4][4];
    float accr[4][4];
#pragma unroll
    for (int i = 0; i < 4; i++)
#pragma unroll
        for (int j = 0; j < 4; j++) { accl[i][j] = 0.f; accr[i][j] = 0.f; }

    for (int k0 = 0; k0 < 128; k0 += 32) {
        __syncthreads();   // covers W staging (iter 0) and prior compute reads
        // stage h slice: 128 rows x 32 k = 1024 float4, 4 per thread
#pragma unroll
        for (int i = 0; i < 4; i++) {
            int q   = t + i * 256;
            int row = q >> 3;
            int kq  = (q & 7) << 2;
            float4 v = make_float4(0.f, 0.f, 0.f, 0.f);
            int gr = row0 + row;
            if (gr < n) v = *(const float4*)(h + (size_t)gr * FDIM + k0 + kq);
            *(float4*)(xs + row * 36 + kq) = v;
        }
        __syncthreads();

#pragma unroll
        for (int kk = 0; kk < 32; kk++) {
            float a[4];
#pragma unroll
            for (int i = 0; i < 4; i++) a[i] = xs[(ty * 4 + i) * 36 + kk];
            float4 bl = *(const float4*)(wls + (k0 + kk) * 32 + tx * 4);
            float4 br = *(const float4*)(wrs + (k0 + kk) * 32 + tx * 4);
            float blv[4] = {bl.x, bl.y, bl.z, bl.w};
            float brv[4] = {br.x, br.y, br.z, br.w};
#pragma unroll
            for (int i = 0; i < 4; i++)
#pragma unroll
                for (int j = 0; j < 4; j++) {
                    accl[i][j] = fmaf(a[i], blv[j], accl[i][j]);
                    accr[i][j] = fmaf(a[i], brv[j], accr[i][j]);
                }
        }
    }

#pragma unroll
    for (int i = 0; i < 4; i++) {
        int gr = row0 + ty * 4 + i;
        if (gr < n) {
            *(float4*)(z + (size_t)gr * CDIM + tx * 4) =
                make_float4(accl[i][0], accl[i][1], accl[i][2], accl[i][3]);
            *(float4*)(r + (size_t)gr * CDIM + tx * 4) =
                make_float4(accr[i][0], accr[i][1], accr[i][2], accr[i][3]);
        }
    }
}

// ---- combine2: out = inv_deg * sum_j z2[j] + r2 + b2 ----------------------

__global__ __launch_bounds__(256) void combine2_kernel(
        const float* __restrict__ z2, const int* __restrict__ rowptr,
        const int* __restrict__ deg, const int* __restrict__ nbr,
        const float* __restrict__ inv_deg, const float* __restrict__ b2,
        const float* __restrict__ r2, float* __restrict__ out, int n) {
    int i = blockIdx.x * 8 + (threadIdx.x >> 5);
    int f = threadIdx.x & 31;
    if (i >= n) return;
    int start = rowptr[i];
    int d     = deg[i];
    float s = 0.f;
    for (int e = 0; e < d; e++) {
        int j = nbr[start + e];
        s += z2[(size_t)j * CDIM + f];
    }
    out[(size_t)i * CDIM + f] = s * inv_deg[i] + r2[(size_t)i * CDIM + f] + b2[f];
}

// ---------------------------------------------------------------------------

extern "C" void kernel_launch(void* const* d_in, const int* in_sizes, int n_in,
                              void* d_out, int out_size, void* d_ws, size_t ws_size,
                              hipStream_t stream) {
    const float* x   = (const float*)d_in[0];
    const int*   ei  = (const int*)d_in[1];     // int64 in reference -> int32 here
    const float* W1l = (const float*)d_in[2];
    const float* b1  = (const float*)d_in[3];
    const float* W1r = (const float*)d_in[4];
    const float* W2l = (const float*)d_in[5];
    const float* b2  = (const float*)d_in[6];
    const float* W2r = (const float*)d_in[7];

    const int N = in_sizes[0] / FDIM;
    const int E = in_sizes[1] / 2;
    const int* src = ei;
    const int* dst = ei + E;

    char* p = (char*)d_ws;
    int*   deg     = (int*)p;   p += (size_t)N * sizeof(int);
    int*   cursor  = (int*)p;   p += (size_t)N * sizeof(int);
    int*   rowptr  = (int*)p;   p += (size_t)N * sizeof(int);
    float* inv_deg = (float*)p; p += (size_t)N * sizeof(float);
    int*   nbr     = (int*)p;   p += (size_t)((E + 3) / 4 * 4) * sizeof(int);
    float* y1      = (float*)p; p += (size_t)N * FDIM * sizeof(float);
    float* r1      = (float*)p; p += (size_t)N * FDIM * sizeof(float);  // becomes h in-place
    // z2/r2 alias y1's region: y1 is dead after combine1, and z2+r2 (25.6MB)
    // fit inside y1 (51.2MB). Keeps peak ws at ~106MB.
    float* z2      = y1;
    float* r2      = y1 + (size_t)N * CDIM;

    // deg and cursor are adjacent: one async memset zeroes both
    hipMemsetAsync(deg, 0, 2 * (size_t)N * sizeof(int), stream);

    deg_kernel <<<(E + 255) / 256, 256, 0, stream>>>(dst, deg, E, N);
    scan_kernel<<<1, 256, 0, stream>>>(deg, rowptr, inv_deg, N);
    fill_kernel<<<(E + 255) / 256, 256, 0, stream>>>(src, dst, rowptr, cursor, nbr, E, N);

    gemm1_kernel   <<<(N + 63) / 64, 256, 0, stream>>>(x, W1l, W1r, y1, r1, N);
    combine1_kernel<<<N, 128, 0, stream>>>(y1, rowptr, deg, nbr, inv_deg, b1, r1, N);
    gemm2_kernel   <<<(N + 127) / 128, 256, 0, stream>>>(r1, W2l, W2r, z2, r2, N);
    combine2_kernel<<<(N + 7) / 8, 256, 0, stream>>>(z2, rowptr, deg, nbr, inv_deg, b2, r2,
                                                     (float*)d_out, N);
}

// Round 3
// 422.889 us; speedup vs baseline: 1.5002x; 1.5002x over previous
//
#include <hip/hip_runtime.h>
#include <hip/hip_bf16.h>

// ---------------------------------------------------------------------------
// GraphSAGE 2-layer: out = sage2( relu(sage1(x)) )
// sage(h, Wl, bl, Wr) = mean_agg(h) @ Wl + bl + h @ Wr
// Linearity: mean_agg(h) @ W == mean_agg(h @ W) -> transform first, then
// aggregate; layer-2 aggregation moves 32 floats/edge, not 128.
// R2 fix: single-block serial scan was 232us (37% of total) -> 3-phase
// hierarchical scan across the grid.
// ---------------------------------------------------------------------------

#define FDIM 128
#define CDIM 32
#define SCAN_CHUNK 1024   // elements per block in the scan (256 thr x 4)

// ---- CSR build ------------------------------------------------------------

__global__ void deg_kernel(const int* __restrict__ dst, int* __restrict__ deg,
                           int E, int n) {
    int e = blockIdx.x * 256 + threadIdx.x;
    if (e < E) {
        int d = dst[e];
        if (d >= 0 && d < n) atomicAdd(&deg[d], 1);
    }
}

// phase 1: per-block reduction of a 1024-element chunk -> partials[block]
__global__ __launch_bounds__(256) void scan1_kernel(
        const int* __restrict__ deg, int* __restrict__ partials, int n) {
    __shared__ int red[256];
    int t = threadIdx.x;
    int base = blockIdx.x * SCAN_CHUNK + t * 4;
    int s = 0;
    if (base + 3 < n) {
        int4 v = *(const int4*)(deg + base);
        s = v.x + v.y + v.z + v.w;
    } else {
        for (int i = 0; i < 4; i++) if (base + i < n) s += deg[base + i];
    }
    red[t] = s;
    __syncthreads();
#pragma unroll
    for (int off = 128; off > 0; off >>= 1) {
        if (t < off) red[t] += red[t + off];
        __syncthreads();
    }
    if (t == 0) partials[blockIdx.x] = red[0];
}

// phase 2: single block exclusive scan over B (<=256) partials, in place
__global__ __launch_bounds__(256) void scan2_kernel(int* __restrict__ partials, int B) {
    __shared__ int s[256];
    int t = threadIdx.x;
    s[t] = (t < B) ? partials[t] : 0;
    __syncthreads();
#pragma unroll
    for (int off = 1; off < 256; off <<= 1) {
        int u = (t >= off) ? s[t - off] : 0;
        __syncthreads();
        s[t] += u;
        __syncthreads();
    }
    if (t < B) partials[t] = (t == 0) ? 0 : s[t - 1];   // exclusive
}

// phase 3: per-block exclusive scan + global offset -> rowptr, inv_deg
__global__ __launch_bounds__(256) void scan3_kernel(
        const int* __restrict__ deg, const int* __restrict__ partials,
        int* __restrict__ rowptr, float* __restrict__ inv_deg, int n) {
    __shared__ int s[256];
    int t = threadIdx.x;
    int base = blockIdx.x * SCAN_CHUNK + t * 4;
    int d0 = 0, d1 = 0, d2 = 0, d3 = 0;
    if (base + 3 < n) {
        int4 v = *(const int4*)(deg + base);
        d0 = v.x; d1 = v.y; d2 = v.z; d3 = v.w;
    } else {
        if (base + 0 < n) d0 = deg[base + 0];
        if (base + 1 < n) d1 = deg[base + 1];
        if (base + 2 < n) d2 = deg[base + 2];
        if (base + 3 < n) d3 = deg[base + 3];
    }
    s[t] = d0 + d1 + d2 + d3;
    __syncthreads();
#pragma unroll
    for (int off = 1; off < 256; off <<= 1) {
        int u = (t >= off) ? s[t - off] : 0;
        __syncthreads();
        s[t] += u;
        __syncthreads();
    }
    int run = partials[blockIdx.x] + ((t == 0) ? 0 : s[t - 1]);
    int dd[4] = {d0, d1, d2, d3};
#pragma unroll
    for (int i = 0; i < 4; i++) {
        if (base + i < n) {
            rowptr[base + i]  = run;
            inv_deg[base + i] = 1.0f / (float)(dd[i] > 0 ? dd[i] : 1);
            run += dd[i];
        }
    }
}

__global__ void fill_kernel(const int* __restrict__ src, const int* __restrict__ dst,
                            const int* __restrict__ rowptr, int* __restrict__ cursor,
                            int* __restrict__ nbr, int E, int n) {
    int e = blockIdx.x * 256 + threadIdx.x;
    if (e < E) {
        int s = src[e];
        int d = dst[e];
        if (d >= 0 && d < n) {
            int p = atomicAdd(&cursor[d], 1);
            nbr[rowptr[d] + p] = s;
        }
    }
}

// ---- GEMM1: y = x @ W1l, r = x @ W1r  ([N,128] @ [128,128] x2) ------------

__global__ __launch_bounds__(256) void gemm1_kernel(
        const float* __restrict__ x, const float* __restrict__ Wl,
        const float* __restrict__ Wr, float* __restrict__ y,
        float* __restrict__ r, int n) {
    __shared__ float xs[64 * 36];      // stride 36: 16B-aligned, conflict-light
    __shared__ float wls[32 * 128];
    __shared__ float wrs[32 * 128];

    const int t  = threadIdx.x;
    const int tx = t & 15;
    const int ty = t >> 4;
    const int row0 = blockIdx.x * 64;

    float accl[4][8];
    float accr[4][8];
#pragma unroll
    for (int i = 0; i < 4; i++)
#pragma unroll
        for (int j = 0; j < 8; j++) { accl[i][j] = 0.f; accr[i][j] = 0.f; }

    for (int k0 = 0; k0 < 128; k0 += 32) {
        __syncthreads();
#pragma unroll
        for (int i = 0; i < 2; i++) {
            int q   = t + i * 256;
            int row = q >> 3;
            int kq  = (q & 7) << 2;
            float4 v = make_float4(0.f, 0.f, 0.f, 0.f);
            int gr = row0 + row;
            if (gr < n) v = *(const float4*)(x + (size_t)gr * FDIM + k0 + kq);
            *(float4*)(xs + row * 36 + kq) = v;
        }
#pragma unroll
        for (int i = 0; i < 4; i++) {
            int q    = t + i * 256;
            int wrow = q >> 5;
            int wc   = (q & 31) << 2;
            *(float4*)(wls + wrow * 128 + wc) = *(const float4*)(Wl + (k0 + wrow) * 128 + wc);
            *(float4*)(wrs + wrow * 128 + wc) = *(const float4*)(Wr + (k0 + wrow) * 128 + wc);
        }
        __syncthreads();

#pragma unroll
        for (int kk = 0; kk < 32; kk++) {
            float a[4];
#pragma unroll
            for (int i = 0; i < 4; i++) a[i] = xs[(ty * 4 + i) * 36 + kk];
            float4 bl0 = *(const float4*)(wls + kk * 128 + tx * 8);
            float4 bl1 = *(const float4*)(wls + kk * 128 + tx * 8 + 4);
            float4 br0 = *(const float4*)(wrs + kk * 128 + tx * 8);
            float4 br1 = *(const float4*)(wrs + kk * 128 + tx * 8 + 4);
            float bl[8] = {bl0.x, bl0.y, bl0.z, bl0.w, bl1.x, bl1.y, bl1.z, bl1.w};
            float br[8] = {br0.x, br0.y, br0.z, br0.w, br1.x, br1.y, br1.z, br1.w};
#pragma unroll
            for (int i = 0; i < 4; i++)
#pragma unroll
                for (int j = 0; j < 8; j++) {
                    accl[i][j] = fmaf(a[i], bl[j], accl[i][j]);
                    accr[i][j] = fmaf(a[i], br[j], accr[i][j]);
                }
        }
    }

#pragma unroll
    for (int i = 0; i < 4; i++) {
        int gr = row0 + ty * 4 + i;
        if (gr < n) {
            float* yp = y + (size_t)gr * FDIM + tx * 8;
            float* rp = r + (size_t)gr * FDIM + tx * 8;
            *(float4*)(yp)     = make_float4(accl[i][0], accl[i][1], accl[i][2], accl[i][3]);
            *(float4*)(yp + 4) = make_float4(accl[i][4], accl[i][5], accl[i][6], accl[i][7]);
            *(float4*)(rp)     = make_float4(accr[i][0], accr[i][1], accr[i][2], accr[i][3]);
            *(float4*)(rp + 4) = make_float4(accr[i][4], accr[i][5], accr[i][6], accr[i][7]);
        }
    }
}

// ---- combine1: h = relu(inv_deg * sum_j y1[j] + r1 + b1), in place over r1 -

__global__ __launch_bounds__(128) void combine1_kernel(
        const float* __restrict__ y1, const int* __restrict__ rowptr,
        const int* __restrict__ deg, const int* __restrict__ nbr,
        const float* __restrict__ inv_deg, const float* __restrict__ b1,
        float* __restrict__ h /* == r1, in-place */, int n) {
    int i = blockIdx.x;
    int f = threadIdx.x;
    int start = rowptr[i];
    int d     = deg[i];
    float s = 0.f;
    for (int e = 0; e < d; e++) {
        int j = nbr[start + e];
        s += y1[(size_t)j * FDIM + f];
    }
    float v = s * inv_deg[i] + h[(size_t)i * FDIM + f] + b1[f];
    h[(size_t)i * FDIM + f] = v > 0.f ? v : 0.f;
}

// ---- GEMM2: z = h @ W2l, r = h @ W2r  ([N,128] @ [128,32] x2) -------------

__global__ __launch_bounds__(256) void gemm2_kernel(
        const float* __restrict__ h, const float* __restrict__ Wl,
        const float* __restrict__ Wr, float* __restrict__ z,
        float* __restrict__ r, int n) {
    __shared__ float xs[128 * 36];
    __shared__ float wls[128 * 32];
    __shared__ float wrs[128 * 32];

    const int t  = threadIdx.x;
    const int tx = t & 7;
    const int ty = t >> 3;
    const int row0 = blockIdx.x * 128;

#pragma unroll
    for (int i = 0; i < 4; i++) {
        int q    = t + i * 256;
        int wrow = q >> 3;
        int wc   = (q & 7) << 2;
        *(float4*)(wls + wrow * 32 + wc) = *(const float4*)(Wl + wrow * 32 + wc);
        *(float4*)(wrs + wrow * 32 + wc) = *(const float4*)(Wr + wrow * 32 + wc);
    }

    float accl[4][4];
    float accr[4][4];
#pragma unroll
    for (int i = 0; i < 4; i++)
#pragma unroll
        for (int j = 0; j < 4; j++) { accl[i][j] = 0.f; accr[i][j] = 0.f; }

    for (int k0 = 0; k0 < 128; k0 += 32) {
        __syncthreads();   // covers W staging (iter 0) and prior compute reads
#pragma unroll
        for (int i = 0; i < 4; i++) {
            int q   = t + i * 256;
            int row = q >> 3;
            int kq  = (q & 7) << 2;
            float4 v = make_float4(0.f, 0.f, 0.f, 0.f);
            int gr = row0 + row;
            if (gr < n) v = *(const float4*)(h + (size_t)gr * FDIM + k0 + kq);
            *(float4*)(xs + row * 36 + kq) = v;
        }
        __syncthreads();

#pragma unroll
        for (int kk = 0; kk < 32; kk++) {
            float a[4];
#pragma unroll
            for (int i = 0; i < 4; i++) a[i] = xs[(ty * 4 + i) * 36 + kk];
            float4 bl = *(const float4*)(wls + (k0 + kk) * 32 + tx * 4);
            float4 br = *(const float4*)(wrs + (k0 + kk) * 32 + tx * 4);
            float blv[4] = {bl.x, bl.y, bl.z, bl.w};
            float brv[4] = {br.x, br.y, br.z, br.w};
#pragma unroll
            for (int i = 0; i < 4; i++)
#pragma unroll
                for (int j = 0; j < 4; j++) {
                    accl[i][j] = fmaf(a[i], blv[j], accl[i][j]);
                    accr[i][j] = fmaf(a[i], brv[j], accr[i][j]);
                }
        }
    }

#pragma unroll
    for (int i = 0; i < 4; i++) {
        int gr = row0 + ty * 4 + i;
        if (gr < n) {
            *(float4*)(z + (size_t)gr * CDIM + tx * 4) =
                make_float4(accl[i][0], accl[i][1], accl[i][2], accl[i][3]);
            *(float4*)(r + (size_t)gr * CDIM + tx * 4) =
                make_float4(accr[i][0], accr[i][1], accr[i][2], accr[i][3]);
        }
    }
}

// ---- combine2: out = inv_deg * sum_j z2[j] + r2 + b2 ----------------------

__global__ __launch_bounds__(256) void combine2_kernel(
        const float* __restrict__ z2, const int* __restrict__ rowptr,
        const int* __restrict__ deg, const int* __restrict__ nbr,
        const float* __restrict__ inv_deg, const float* __restrict__ b2,
        const float* __restrict__ r2, float* __restrict__ out, int n) {
    int i = blockIdx.x * 8 + (threadIdx.x >> 5);
    int f = threadIdx.x & 31;
    if (i >= n) return;
    int start = rowptr[i];
    int d     = deg[i];
    float s = 0.f;
    for (int e = 0; e < d; e++) {
        int j = nbr[start + e];
        s += z2[(size_t)j * CDIM + f];
    }
    out[(size_t)i * CDIM + f] = s * inv_deg[i] + r2[(size_t)i * CDIM + f] + b2[f];
}

// ---------------------------------------------------------------------------

extern "C" void kernel_launch(void* const* d_in, const int* in_sizes, int n_in,
                              void* d_out, int out_size, void* d_ws, size_t ws_size,
                              hipStream_t stream) {
    const float* x   = (const float*)d_in[0];
    const int*   ei  = (const int*)d_in[1];     // int64 in reference -> int32 here
    const float* W1l = (const float*)d_in[2];
    const float* b1  = (const float*)d_in[3];
    const float* W1r = (const float*)d_in[4];
    const float* W2l = (const float*)d_in[5];
    const float* b2  = (const float*)d_in[6];
    const float* W2r = (const float*)d_in[7];

    const int N = in_sizes[0] / FDIM;
    const int E = in_sizes[1] / 2;
    const int* src = ei;
    const int* dst = ei + E;

    char* p = (char*)d_ws;
    int*   deg      = (int*)p;   p += (size_t)N * sizeof(int);
    int*   cursor   = (int*)p;   p += (size_t)N * sizeof(int);
    int*   rowptr   = (int*)p;   p += (size_t)N * sizeof(int);
    float* inv_deg  = (float*)p; p += (size_t)N * sizeof(float);
    int*   partials = (int*)p;   p += 256 * sizeof(int);
    int*   nbr      = (int*)p;   p += (size_t)((E + 3) / 4 * 4) * sizeof(int);
    float* y1       = (float*)p; p += (size_t)N * FDIM * sizeof(float);
    float* r1       = (float*)p; p += (size_t)N * FDIM * sizeof(float);  // becomes h in-place
    // z2/r2 alias y1's region: y1 is dead after combine1, z2+r2 (25.6MB) fits.
    float* z2       = y1;
    float* r2       = y1 + (size_t)N * CDIM;

    const int SB = (N + SCAN_CHUNK - 1) / SCAN_CHUNK;   // scan blocks (98 @ N=100k)

    // deg and cursor are adjacent: one async memset zeroes both
    hipMemsetAsync(deg, 0, 2 * (size_t)N * sizeof(int), stream);

    deg_kernel  <<<(E + 255) / 256, 256, 0, stream>>>(dst, deg, E, N);
    scan1_kernel<<<SB, 256, 0, stream>>>(deg, partials, N);
    scan2_kernel<<<1, 256, 0, stream>>>(partials, SB);
    scan3_kernel<<<SB, 256, 0, stream>>>(deg, partials, rowptr, inv_deg, N);
    fill_kernel <<<(E + 255) / 256, 256, 0, stream>>>(src, dst, rowptr, cursor, nbr, E, N);

    gemm1_kernel   <<<(N + 63) / 64, 256, 0, stream>>>(x, W1l, W1r, y1, r1, N);
    combine1_kernel<<<N, 128, 0, stream>>>(y1, rowptr, deg, nbr, inv_deg, b1, r1, N);
    gemm2_kernel   <<<(N + 127) / 128, 256, 0, stream>>>(r1, W2l, W2r, z2, r2, N);
    combine2_kernel<<<(N + 7) / 8, 256, 0, stream>>>(z2, rowptr, deg, nbr, inv_deg, b2, r2,
                                                     (float*)d_out, N);
}

// Round 4
// 344.799 us; speedup vs baseline: 1.8400x; 1.2265x over previous
//
#include <hip/hip_runtime.h>
#include <hip/hip_bf16.h>

// ---------------------------------------------------------------------------
// GraphSAGE 2-layer, bf16-MFMA edition.
//   h   = relu( mean_nbr(x) @ W1l + x @ W1r + b1 )     (aggregate-first, fused)
//   out = mean_nbr(h @ W2l) + h @ W2r + b2             (transform-first: 32 c/edge)
// All GEMMs: mfma_f32_16x16x32_bf16, fragments loaded DIRECTLY from global
// (W pre-transposed to [n][k] bf16 -> contiguous 16B frags; no LDS, no barriers).
// fp32 accumulate; x/W converted to bf16 once (threshold 4.3e-2 is bf16-sized).
// R3 post-mortem: fp32 VALU gemm1 was 115us @ MfmaUtil=0 + 1.3e7 bank conflicts;
// combine1 gathered 307MB of fp32. This round: MFMA + bf16 gather (154MB).
// ---------------------------------------------------------------------------

#define FDIM 128
#define CDIM 32
#define SCAN_CHUNK 1024

typedef __attribute__((ext_vector_type(8))) short short8;
typedef __attribute__((ext_vector_type(4))) float f32x4;
typedef unsigned short ushort_t;
typedef unsigned int uint_t;

static __device__ __forceinline__ ushort_t f2bf(float f) {
    uint_t u = __float_as_uint(f);
    u += 0x7fffu + ((u >> 16) & 1u);       // round-to-nearest-even
    return (ushort_t)(u >> 16);
}
static __device__ __forceinline__ float bf2f_lo(uint_t u) {
    return __uint_as_float(u << 16);
}
static __device__ __forceinline__ float bf2f_hi(uint_t u) {
    return __uint_as_float(u & 0xffff0000u);
}

// ---- CSR build ------------------------------------------------------------

__global__ void deg_kernel(const int* __restrict__ dst, int* __restrict__ deg,
                           int E, int n) {
    int e = blockIdx.x * 256 + threadIdx.x;
    if (e < E) {
        int d = dst[e];
        if (d >= 0 && d < n) atomicAdd(&deg[d], 1);
    }
}

__global__ __launch_bounds__(256) void scan1_kernel(
        const int* __restrict__ deg, int* __restrict__ partials, int n) {
    __shared__ int red[256];
    int t = threadIdx.x;
    int base = blockIdx.x * SCAN_CHUNK + t * 4;
    int s = 0;
    if (base + 3 < n) {
        int4 v = *(const int4*)(deg + base);
        s = v.x + v.y + v.z + v.w;
    } else {
        for (int i = 0; i < 4; i++) if (base + i < n) s += deg[base + i];
    }
    red[t] = s;
    __syncthreads();
#pragma unroll
    for (int off = 128; off > 0; off >>= 1) {
        if (t < off) red[t] += red[t + off];
        __syncthreads();
    }
    if (t == 0) partials[blockIdx.x] = red[0];
}

__global__ __launch_bounds__(256) void scan2_kernel(int* __restrict__ partials, int B) {
    __shared__ int s[256];
    int t = threadIdx.x;
    s[t] = (t < B) ? partials[t] : 0;
    __syncthreads();
#pragma unroll
    for (int off = 1; off < 256; off <<= 1) {
        int u = (t >= off) ? s[t - off] : 0;
        __syncthreads();
        s[t] += u;
        __syncthreads();
    }
    if (t < B) partials[t] = (t == 0) ? 0 : s[t - 1];
}

__global__ __launch_bounds__(256) void scan3_kernel(
        const int* __restrict__ deg, const int* __restrict__ partials,
        int* __restrict__ rowptr, float* __restrict__ inv_deg, int n) {
    __shared__ int s[256];
    int t = threadIdx.x;
    int base = blockIdx.x * SCAN_CHUNK + t * 4;
    int d0 = 0, d1 = 0, d2 = 0, d3 = 0;
    if (base + 3 < n) {
        int4 v = *(const int4*)(deg + base);
        d0 = v.x; d1 = v.y; d2 = v.z; d3 = v.w;
    } else {
        if (base + 0 < n) d0 = deg[base + 0];
        if (base + 1 < n) d1 = deg[base + 1];
        if (base + 2 < n) d2 = deg[base + 2];
        if (base + 3 < n) d3 = deg[base + 3];
    }
    s[t] = d0 + d1 + d2 + d3;
    __syncthreads();
#pragma unroll
    for (int off = 1; off < 256; off <<= 1) {
        int u = (t >= off) ? s[t - off] : 0;
        __syncthreads();
        s[t] += u;
        __syncthreads();
    }
    int run = partials[blockIdx.x] + ((t == 0) ? 0 : s[t - 1]);
    int dd[4] = {d0, d1, d2, d3};
#pragma unroll
    for (int i = 0; i < 4; i++) {
        if (base + i < n) {
            rowptr[base + i]  = run;
            inv_deg[base + i] = 1.0f / (float)(dd[i] > 0 ? dd[i] : 1);
            run += dd[i];
        }
    }
}

__global__ void fill_kernel(const int* __restrict__ src, const int* __restrict__ dst,
                            const int* __restrict__ rowptr, int* __restrict__ cursor,
                            int* __restrict__ nbr, int E, int n) {
    int e = blockIdx.x * 256 + threadIdx.x;
    if (e < E) {
        int s = src[e];
        int d = dst[e];
        if (d >= 0 && d < n) {
            int p = atomicAdd(&cursor[d], 1);
            nbr[rowptr[d] + p] = s;
        }
    }
}

// ---- conversions ----------------------------------------------------------

// x fp32 -> bf16, 8 elems/thread
__global__ __launch_bounds__(256) void cvt_x_kernel(
        const float* __restrict__ x, uint_t* __restrict__ xb4 /* as uint4 */,
        long long total8 /* total/8 */) {
    long long i = (long long)blockIdx.x * 256 + threadIdx.x;
    if (i >= total8) return;
    const float4* p = (const float4*)x + i * 2;
    float4 v0 = p[0], v1 = p[1];
    uint4 o;
    o.x = (uint_t)f2bf(v0.x) | ((uint_t)f2bf(v0.y) << 16);
    o.y = (uint_t)f2bf(v0.z) | ((uint_t)f2bf(v0.w) << 16);
    o.z = (uint_t)f2bf(v1.x) | ((uint_t)f2bf(v1.y) << 16);
    o.w = (uint_t)f2bf(v1.z) | ((uint_t)f2bf(v1.w) << 16);
    ((uint4*)xb4)[i] = o;
}

// W [K,Nc] fp32 row-major -> Wt [Nc,K] bf16 (so B-frags are 16B-contiguous in k)
__global__ __launch_bounds__(256) void cvt_w_kernel(
        const float* __restrict__ w, ushort_t* __restrict__ wt, int K, int Nc) {
    int idx = blockIdx.x * 256 + threadIdx.x;
    if (idx >= K * Nc) return;
    int nn = idx / K, kk = idx % K;
    wt[nn * K + kk] = f2bf(w[kk * Nc + nn]);
}

// ---- agg1: aggb[i] = bf16( mean_{j in N(i)} xb[j] ), one wave per node ----

__global__ __launch_bounds__(256) void agg1_kernel(
        const uint_t* __restrict__ xbu /* N x 64 uints */,
        const int* __restrict__ rowptr, const int* __restrict__ deg,
        const int* __restrict__ nbr, const float* __restrict__ inv_deg,
        uint_t* __restrict__ aggbu, int n) {
    int t = threadIdx.x;
    int i = blockIdx.x * 4 + (t >> 6);
    if (i >= n) return;
    int lane  = t & 63;
    int start = rowptr[i];
    int d     = deg[i];
    float s0 = 0.f, s1 = 0.f;
    for (int e = 0; e < d; e++) {
        int j = nbr[start + e];
        uint_t u = xbu[(size_t)j * 64 + lane];
        s0 += bf2f_lo(u);
        s1 += bf2f_hi(u);
    }
    float inv = inv_deg[i];
    s0 *= inv; s1 *= inv;
    aggbu[(size_t)i * 64 + lane] = (uint_t)f2bf(s0) | ((uint_t)f2bf(s1) << 16);
}

// ---- gemm1f: hb = relu( aggb@W1l + xb@W1r + b1 ), bf16 out ----------------
// 256 thr = 4 waves; block = 64 rows x 128 cols; wave w: cols w*32..w*32+31.
// MFMA 16x16x32 bf16, frags straight from global. No LDS, no __syncthreads.

__global__ __launch_bounds__(256) void gemm1f_kernel(
        const ushort_t* __restrict__ xb, const ushort_t* __restrict__ aggb,
        const ushort_t* __restrict__ w1lt, const ushort_t* __restrict__ w1rt,
        const float* __restrict__ b1, ushort_t* __restrict__ hb, int n) {
    const int t    = threadIdx.x;
    const int wave = t >> 6;
    const int lane = t & 63;
    const int quad = lane >> 4;
    const int l16  = lane & 15;
    const int row0 = blockIdx.x * 64;
    const int c0   = wave * 32;

    float bias[2];
#pragma unroll
    for (int c = 0; c < 2; c++) bias[c] = b1[c0 + c * 16 + l16];

    f32x4 acc[4][2];
#pragma unroll
    for (int r = 0; r < 4; r++)
#pragma unroll
        for (int c = 0; c < 2; c++) acc[r][c] = (f32x4){0.f, 0.f, 0.f, 0.f};

#pragma unroll
    for (int k0 = 0; k0 < FDIM; k0 += 32) {
        short8 a1[4], a2[4], bl[2], br[2];
#pragma unroll
        for (int r = 0; r < 4; r++) {
            int row = row0 + r * 16 + l16;
            if (row >= n) row = n - 1;                       // clamp; store guarded
            size_t off = (size_t)row * FDIM + k0 + quad * 8;
            a1[r] = *(const short8*)(aggb + off);
            a2[r] = *(const short8*)(xb + off);
        }
#pragma unroll
        for (int c = 0; c < 2; c++) {
            size_t woff = (size_t)(c0 + c * 16 + l16) * FDIM + k0 + quad * 8;
            bl[c] = *(const short8*)(w1lt + woff);
            br[c] = *(const short8*)(w1rt + woff);
        }
#pragma unroll
        for (int r = 0; r < 4; r++)
#pragma unroll
            for (int c = 0; c < 2; c++) {
                acc[r][c] = __builtin_amdgcn_mfma_f32_16x16x32_bf16(a1[r], bl[c], acc[r][c], 0, 0, 0);
                acc[r][c] = __builtin_amdgcn_mfma_f32_16x16x32_bf16(a2[r], br[c], acc[r][c], 0, 0, 0);
            }
    }

    // C/D: col = lane&15, row = quad*4 + reg  (m89/m91-verified)
#pragma unroll
    for (int r = 0; r < 4; r++)
#pragma unroll
        for (int reg = 0; reg < 4; reg++) {
            int row = row0 + r * 16 + quad * 4 + reg;
            if (row < n) {
#pragma unroll
                for (int c = 0; c < 2; c++) {
                    float v = acc[r][c][reg] + bias[c];
                    v = v > 0.f ? v : 0.f;
                    hb[(size_t)row * FDIM + c0 + c * 16 + l16] = f2bf(v);
                }
            }
        }
}

// ---- gemm2: z2 = hb@W2l, r2 = hb@W2r (fp32 out, [N,32]) -------------------
// 256 thr = 4 waves; each wave owns 64 rows; block = 256 rows.

__global__ __launch_bounds__(256) void gemm2_kernel(
        const ushort_t* __restrict__ hb,
        const ushort_t* __restrict__ w2lt, const ushort_t* __restrict__ w2rt,
        float* __restrict__ z2, float* __restrict__ r2, int n) {
    const int t    = threadIdx.x;
    const int wave = t >> 6;
    const int lane = t & 63;
    const int quad = lane >> 4;
    const int l16  = lane & 15;
    const int row0 = blockIdx.x * 256 + wave * 64;

    f32x4 accl[4][2], accr[4][2];
#pragma unroll
    for (int r = 0; r < 4; r++)
#pragma unroll
        for (int c = 0; c < 2; c++) {
            accl[r][c] = (f32x4){0.f, 0.f, 0.f, 0.f};
            accr[r][c] = (f32x4){0.f, 0.f, 0.f, 0.f};
        }

#pragma unroll
    for (int k0 = 0; k0 < FDIM; k0 += 32) {
        short8 a[4], bl[2], br[2];
#pragma unroll
        for (int r = 0; r < 4; r++) {
            int row = row0 + r * 16 + l16;
            if (row >= n) row = n - 1;
            a[r] = *(const short8*)(hb + (size_t)row * FDIM + k0 + quad * 8);
        }
#pragma unroll
        for (int c = 0; c < 2; c++) {
            size_t woff = (size_t)(c * 16 + l16) * FDIM + k0 + quad * 8;
            bl[c] = *(const short8*)(w2lt + woff);
            br[c] = *(const short8*)(w2rt + woff);
        }
#pragma unroll
        for (int r = 0; r < 4; r++)
#pragma unroll
            for (int c = 0; c < 2; c++) {
                accl[r][c] = __builtin_amdgcn_mfma_f32_16x16x32_bf16(a[r], bl[c], accl[r][c], 0, 0, 0);
                accr[r][c] = __builtin_amdgcn_mfma_f32_16x16x32_bf16(a[r], br[c], accr[r][c], 0, 0, 0);
            }
    }

#pragma unroll
    for (int r = 0; r < 4; r++)
#pragma unroll
        for (int reg = 0; reg < 4; reg++) {
            int row = row0 + r * 16 + quad * 4 + reg;
            if (row < n) {
#pragma unroll
                for (int c = 0; c < 2; c++) {
                    z2[(size_t)row * CDIM + c * 16 + l16] = accl[r][c][reg];
                    r2[(size_t)row * CDIM + c * 16 + l16] = accr[r][c][reg];
                }
            }
        }
}

// ---- combine2: out = inv_deg * sum_j z2[j] + r2 + b2 ----------------------

__global__ __launch_bounds__(256) void combine2_kernel(
        const float* __restrict__ z2, const int* __restrict__ rowptr,
        const int* __restrict__ deg, const int* __restrict__ nbr,
        const float* __restrict__ inv_deg, const float* __restrict__ b2,
        const float* __restrict__ r2, float* __restrict__ out, int n) {
    int i = blockIdx.x * 8 + (threadIdx.x >> 5);
    int f = threadIdx.x & 31;
    if (i >= n) return;
    int start = rowptr[i];
    int d     = deg[i];
    float s = 0.f;
    for (int e = 0; e < d; e++) {
        int j = nbr[start + e];
        s += z2[(size_t)j * CDIM + f];
    }
    out[(size_t)i * CDIM + f] = s * inv_deg[i] + r2[(size_t)i * CDIM + f] + b2[f];
}

// ---------------------------------------------------------------------------

extern "C" void kernel_launch(void* const* d_in, const int* in_sizes, int n_in,
                              void* d_out, int out_size, void* d_ws, size_t ws_size,
                              hipStream_t stream) {
    const float* x   = (const float*)d_in[0];
    const int*   ei  = (const int*)d_in[1];     // int64 in ref -> int32 here
    const float* W1l = (const float*)d_in[2];
    const float* b1  = (const float*)d_in[3];
    const float* W1r = (const float*)d_in[4];
    const float* W2l = (const float*)d_in[5];
    const float* b2  = (const float*)d_in[6];
    const float* W2r = (const float*)d_in[7];

    const int N = in_sizes[0] / FDIM;
    const int E = in_sizes[1] / 2;
    const int* src = ei;
    const int* dst = ei + E;

    char* p = (char*)d_ws;
    int*      deg      = (int*)p;      p += (size_t)N * sizeof(int);
    int*      cursor   = (int*)p;      p += (size_t)N * sizeof(int);
    int*      rowptr   = (int*)p;      p += (size_t)N * sizeof(int);
    float*    inv_deg  = (float*)p;    p += (size_t)N * sizeof(float);
    int*      partials = (int*)p;      p += 256 * sizeof(int);
    ushort_t* w1lt     = (ushort_t*)p; p += FDIM * FDIM * sizeof(ushort_t);
    ushort_t* w1rt     = (ushort_t*)p; p += FDIM * FDIM * sizeof(ushort_t);
    ushort_t* w2lt     = (ushort_t*)p; p += FDIM * CDIM * sizeof(ushort_t);
    ushort_t* w2rt     = (ushort_t*)p; p += FDIM * CDIM * sizeof(ushort_t);
    int*      nbr      = (int*)p;      p += (size_t)((E + 3) / 4 * 4) * sizeof(int);
    ushort_t* xb       = (ushort_t*)p; p += (size_t)N * FDIM * sizeof(ushort_t);
    ushort_t* aggb     = (ushort_t*)p; p += (size_t)N * FDIM * sizeof(ushort_t);
    ushort_t* hb       = (ushort_t*)p; p += (size_t)N * FDIM * sizeof(ushort_t);
    // z2/r2 (12.8MB each) alias aggb (25.6MB): aggb dead after gemm1f.
    float*    z2       = (float*)aggb;
    float*    r2       = (float*)aggb + (size_t)N * CDIM;

    const int SB = (N + SCAN_CHUNK - 1) / SCAN_CHUNK;

    hipMemsetAsync(deg, 0, 2 * (size_t)N * sizeof(int), stream);

    // CSR
    deg_kernel  <<<(E + 255) / 256, 256, 0, stream>>>(dst, deg, E, N);
    scan1_kernel<<<SB, 256, 0, stream>>>(deg, partials, N);
    scan2_kernel<<<1, 256, 0, stream>>>(partials, SB);
    scan3_kernel<<<SB, 256, 0, stream>>>(deg, partials, rowptr, inv_deg, N);
    fill_kernel <<<(E + 255) / 256, 256, 0, stream>>>(src, dst, rowptr, cursor, nbr, E, N);

    // bf16 conversions
    long long total8 = (long long)N * FDIM / 8;
    cvt_x_kernel<<<(int)((total8 + 255) / 256), 256, 0, stream>>>(x, (uint_t*)xb, total8);
    cvt_w_kernel<<<(FDIM * FDIM + 255) / 256, 256, 0, stream>>>(W1l, w1lt, FDIM, FDIM);
    cvt_w_kernel<<<(FDIM * FDIM + 255) / 256, 256, 0, stream>>>(W1r, w1rt, FDIM, FDIM);
    cvt_w_kernel<<<(FDIM * CDIM + 255) / 256, 256, 0, stream>>>(W2l, w2lt, FDIM, CDIM);
    cvt_w_kernel<<<(FDIM * CDIM + 255) / 256, 256, 0, stream>>>(W2r, w2rt, FDIM, CDIM);

    // layer 1
    agg1_kernel  <<<(N + 3) / 4, 256, 0, stream>>>((const uint_t*)xb, rowptr, deg, nbr,
                                                   inv_deg, (uint_t*)aggb, N);
    gemm1f_kernel<<<(N + 63) / 64, 256, 0, stream>>>(xb, aggb, w1lt, w1rt, b1, hb, N);

    // layer 2
    gemm2_kernel   <<<(N + 255) / 256, 256, 0, stream>>>(hb, w2lt, w2rt, z2, r2, N);
    combine2_kernel<<<(N + 7) / 8, 256, 0, stream>>>(z2, rowptr, deg, nbr, inv_deg, b2, r2,
                                                     (float*)d_out, N);
}

// Round 5
// 299.144 us; speedup vs baseline: 2.1208x; 1.1526x over previous
//
#include <hip/hip_runtime.h>
#include <hip/hip_bf16.h>

// ---------------------------------------------------------------------------
// GraphSAGE 2-layer, bf16-MFMA edition.
//   h   = relu( mean_nbr(x) @ W1l + x @ W1r + b1 )     (aggregate-first, fused)
//   out = mean_nbr(h @ W2l) + h @ W2r + b2             (transform-first: 32 c/edge)
// R4 post-mortem: agg1 (one wave/node, serial edges) was latency-bound at
// 74us, VALUBusy 17%. R5: 4 edge-groups of 16 lanes per wave -> 4x MLP;
// combine2 gathers bf16 z2 (half traffic) with the same scheme; merged
// small kernels (13 -> 10 launches).
// ---------------------------------------------------------------------------

#define FDIM 128
#define CDIM 32
#define SCAN_CHUNK 1024

typedef __attribute__((ext_vector_type(8))) short short8;
typedef __attribute__((ext_vector_type(4))) float f32x4;
typedef unsigned short ushort_t;
typedef unsigned int uint_t;

static __device__ __forceinline__ ushort_t f2bf(float f) {
    uint_t u = __float_as_uint(f);
    u += 0x7fffu + ((u >> 16) & 1u);       // round-to-nearest-even
    return (ushort_t)(u >> 16);
}
static __device__ __forceinline__ float bf2f_lo(uint_t u) {
    return __uint_as_float(u << 16);
}
static __device__ __forceinline__ float bf2f_hi(uint_t u) {
    return __uint_as_float(u & 0xffff0000u);
}

// ---- prep: x fp32 -> bf16 (blocks [0,CB)) + degree count (blocks [CB,..)) --

__global__ __launch_bounds__(256) void prep_kernel(
        const float* __restrict__ x, uint_t* __restrict__ xb4, long long total8,
        const int* __restrict__ dst, int* __restrict__ deg, int E, int n, int CB) {
    if ((int)blockIdx.x < CB) {
        long long i = (long long)blockIdx.x * 256 + threadIdx.x;
        if (i >= total8) return;
        const float4* p = (const float4*)x + i * 2;
        float4 v0 = p[0], v1 = p[1];
        uint4 o;
        o.x = (uint_t)f2bf(v0.x) | ((uint_t)f2bf(v0.y) << 16);
        o.y = (uint_t)f2bf(v0.z) | ((uint_t)f2bf(v0.w) << 16);
        o.z = (uint_t)f2bf(v1.x) | ((uint_t)f2bf(v1.y) << 16);
        o.w = (uint_t)f2bf(v1.z) | ((uint_t)f2bf(v1.w) << 16);
        ((uint4*)xb4)[i] = o;
    } else {
        int e = ((int)blockIdx.x - CB) * 256 + threadIdx.x;
        if (e < E) {
            int d = dst[e];
            if (d >= 0 && d < n) atomicAdd(&deg[d], 1);
        }
    }
}

// ---- hierarchical scan ----------------------------------------------------

__global__ __launch_bounds__(256) void scan1_kernel(
        const int* __restrict__ deg, int* __restrict__ partials, int n) {
    __shared__ int red[256];
    int t = threadIdx.x;
    int base = blockIdx.x * SCAN_CHUNK + t * 4;
    int s = 0;
    if (base + 3 < n) {
        int4 v = *(const int4*)(deg + base);
        s = v.x + v.y + v.z + v.w;
    } else {
        for (int i = 0; i < 4; i++) if (base + i < n) s += deg[base + i];
    }
    red[t] = s;
    __syncthreads();
#pragma unroll
    for (int off = 128; off > 0; off >>= 1) {
        if (t < off) red[t] += red[t + off];
        __syncthreads();
    }
    if (t == 0) partials[blockIdx.x] = red[0];
}

__global__ __launch_bounds__(256) void scan2_kernel(int* __restrict__ partials, int B) {
    __shared__ int s[256];
    int t = threadIdx.x;
    s[t] = (t < B) ? partials[t] : 0;
    __syncthreads();
#pragma unroll
    for (int off = 1; off < 256; off <<= 1) {
        int u = (t >= off) ? s[t - off] : 0;
        __syncthreads();
        s[t] += u;
        __syncthreads();
    }
    if (t < B) partials[t] = (t == 0) ? 0 : s[t - 1];
}

__global__ __launch_bounds__(256) void scan3_kernel(
        const int* __restrict__ deg, const int* __restrict__ partials,
        int* __restrict__ rowptr, float* __restrict__ inv_deg, int n) {
    __shared__ int s[256];
    int t = threadIdx.x;
    int base = blockIdx.x * SCAN_CHUNK + t * 4;
    int d0 = 0, d1 = 0, d2 = 0, d3 = 0;
    if (base + 3 < n) {
        int4 v = *(const int4*)(deg + base);
        d0 = v.x; d1 = v.y; d2 = v.z; d3 = v.w;
    } else {
        if (base + 0 < n) d0 = deg[base + 0];
        if (base + 1 < n) d1 = deg[base + 1];
        if (base + 2 < n) d2 = deg[base + 2];
        if (base + 3 < n) d3 = deg[base + 3];
    }
    s[t] = d0 + d1 + d2 + d3;
    __syncthreads();
#pragma unroll
    for (int off = 1; off < 256; off <<= 1) {
        int u = (t >= off) ? s[t - off] : 0;
        __syncthreads();
        s[t] += u;
        __syncthreads();
    }
    int run = partials[blockIdx.x] + ((t == 0) ? 0 : s[t - 1]);
    int dd[4] = {d0, d1, d2, d3};
#pragma unroll
    for (int i = 0; i < 4; i++) {
        if (base + i < n) {
            rowptr[base + i]  = run;
            inv_deg[base + i] = 1.0f / (float)(dd[i] > 0 ? dd[i] : 1);
            run += dd[i];
        }
    }
}

__global__ void fill_kernel(const int* __restrict__ src, const int* __restrict__ dst,
                            const int* __restrict__ rowptr, int* __restrict__ cursor,
                            int* __restrict__ nbr, int E, int n) {
    int e = blockIdx.x * 256 + threadIdx.x;
    if (e < E) {
        int s = src[e];
        int d = dst[e];
        if (d >= 0 && d < n) {
            int p = atomicAdd(&cursor[d], 1);
            nbr[rowptr[d] + p] = s;
        }
    }
}

// ---- cvt_w_all: all 4 weight matrices fp32[K,Nc] -> bf16[Nc,K], K=128 -----

__global__ __launch_bounds__(256) void cvt_w_all_kernel(
        const float* __restrict__ W1l, const float* __restrict__ W1r,
        const float* __restrict__ W2l, const float* __restrict__ W2r,
        ushort_t* __restrict__ w1lt, ushort_t* __restrict__ w1rt,
        ushort_t* __restrict__ w2lt, ushort_t* __restrict__ w2rt) {
    int idx = blockIdx.x * 256 + threadIdx.x;
    const float* w; ushort_t* wt; int Nc, local;
    if (idx < 16384)      { w = W1l; wt = w1lt; Nc = 128; local = idx; }
    else if (idx < 32768) { w = W1r; wt = w1rt; Nc = 128; local = idx - 16384; }
    else if (idx < 36864) { w = W2l; wt = w2lt; Nc = 32;  local = idx - 32768; }
    else if (idx < 40960) { w = W2r; wt = w2rt; Nc = 32;  local = idx - 36864; }
    else return;
    int nn = local >> 7, kk = local & 127;
    wt[nn * 128 + kk] = f2bf(w[kk * Nc + nn]);
}

// ---- agg1: aggb[i] = bf16( mean_{j in N(i)} xb[j] ) -----------------------
// One wave per node; 4 groups of 16 lanes process interleaved edges (4x MLP);
// each group reads a full 256B row coalesced; cross-group shuffle reduce.

__global__ __launch_bounds__(256) void agg1_kernel(
        const uint_t* __restrict__ xbu /* N x 64 uints */,
        const int* __restrict__ rowptr, const int* __restrict__ deg,
        const int* __restrict__ nbr, const float* __restrict__ inv_deg,
        uint_t* __restrict__ aggbu, int n) {
    int t = threadIdx.x;
    int i = blockIdx.x * 4 + (t >> 6);
    if (i >= n) return;
    int lane = t & 63;
    int g    = lane >> 4;
    int l16  = lane & 15;
    int start = rowptr[i];
    int d     = deg[i];
    float s[8] = {0.f, 0.f, 0.f, 0.f, 0.f, 0.f, 0.f, 0.f};
    for (int e = g; e < d; e += 4) {
        int j = nbr[start + e];
        uint4 u = *(const uint4*)(xbu + (size_t)j * 64 + l16 * 4);
        s[0] += bf2f_lo(u.x); s[1] += bf2f_hi(u.x);
        s[2] += bf2f_lo(u.y); s[3] += bf2f_hi(u.y);
        s[4] += bf2f_lo(u.z); s[5] += bf2f_hi(u.z);
        s[6] += bf2f_lo(u.w); s[7] += bf2f_hi(u.w);
    }
#pragma unroll
    for (int k = 0; k < 8; k++) {
        s[k] += __shfl_xor(s[k], 16, 64);
        s[k] += __shfl_xor(s[k], 32, 64);
    }
    if (g == 0) {
        float inv = inv_deg[i];
        uint4 o;
        o.x = (uint_t)f2bf(s[0] * inv) | ((uint_t)f2bf(s[1] * inv) << 16);
        o.y = (uint_t)f2bf(s[2] * inv) | ((uint_t)f2bf(s[3] * inv) << 16);
        o.z = (uint_t)f2bf(s[4] * inv) | ((uint_t)f2bf(s[5] * inv) << 16);
        o.w = (uint_t)f2bf(s[6] * inv) | ((uint_t)f2bf(s[7] * inv) << 16);
        *(uint4*)(aggbu + (size_t)i * 64 + l16 * 4) = o;
    }
}

// ---- gemm1f: hb = relu( aggb@W1l + xb@W1r + b1 ), bf16 out ----------------
// 256 thr = 4 waves; block = 64 rows x 128 cols; wave w: cols w*32..w*32+31.
// MFMA 16x16x32 bf16, frags straight from global. No LDS, no barriers.

__global__ __launch_bounds__(256) void gemm1f_kernel(
        const ushort_t* __restrict__ xb, const ushort_t* __restrict__ aggb,
        const ushort_t* __restrict__ w1lt, const ushort_t* __restrict__ w1rt,
        const float* __restrict__ b1, ushort_t* __restrict__ hb, int n) {
    const int t    = threadIdx.x;
    const int wave = t >> 6;
    const int lane = t & 63;
    const int quad = lane >> 4;
    const int l16  = lane & 15;
    const int row0 = blockIdx.x * 64;
    const int c0   = wave * 32;

    float bias[2];
#pragma unroll
    for (int c = 0; c < 2; c++) bias[c] = b1[c0 + c * 16 + l16];

    f32x4 acc[4][2];
#pragma unroll
    for (int r = 0; r < 4; r++)
#pragma unroll
        for (int c = 0; c < 2; c++) acc[r][c] = (f32x4){0.f, 0.f, 0.f, 0.f};

#pragma unroll
    for (int k0 = 0; k0 < FDIM; k0 += 32) {
        short8 a1[4], a2[4], bl[2], br[2];
#pragma unroll
        for (int r = 0; r < 4; r++) {
            int row = row0 + r * 16 + l16;
            if (row >= n) row = n - 1;                       // clamp; store guarded
            size_t off = (size_t)row * FDIM + k0 + quad * 8;
            a1[r] = *(const short8*)(aggb + off);
            a2[r] = *(const short8*)(xb + off);
        }
#pragma unroll
        for (int c = 0; c < 2; c++) {
            size_t woff = (size_t)(c0 + c * 16 + l16) * FDIM + k0 + quad * 8;
            bl[c] = *(const short8*)(w1lt + woff);
            br[c] = *(const short8*)(w1rt + woff);
        }
#pragma unroll
        for (int r = 0; r < 4; r++)
#pragma unroll
            for (int c = 0; c < 2; c++) {
                acc[r][c] = __builtin_amdgcn_mfma_f32_16x16x32_bf16(a1[r], bl[c], acc[r][c], 0, 0, 0);
                acc[r][c] = __builtin_amdgcn_mfma_f32_16x16x32_bf16(a2[r], br[c], acc[r][c], 0, 0, 0);
            }
    }

    // C/D: col = lane&15, row = quad*4 + reg  (m89/m91-verified)
#pragma unroll
    for (int r = 0; r < 4; r++)
#pragma unroll
        for (int reg = 0; reg < 4; reg++) {
            int row = row0 + r * 16 + quad * 4 + reg;
            if (row < n) {
#pragma unroll
                for (int c = 0; c < 2; c++) {
                    float v = acc[r][c][reg] + bias[c];
                    v = v > 0.f ? v : 0.f;
                    hb[(size_t)row * FDIM + c0 + c * 16 + l16] = f2bf(v);
                }
            }
        }
}

// ---- gemm2: z2b = bf16(hb@W2l), r2 = fp32(hb@W2r)  ([N,32]) ---------------

__global__ __launch_bounds__(256) void gemm2_kernel(
        const ushort_t* __restrict__ hb,
        const ushort_t* __restrict__ w2lt, const ushort_t* __restrict__ w2rt,
        ushort_t* __restrict__ z2b, float* __restrict__ r2, int n) {
    const int t    = threadIdx.x;
    const int wave = t >> 6;
    const int lane = t & 63;
    const int quad = lane >> 4;
    const int l16  = lane & 15;
    const int row0 = blockIdx.x * 256 + wave * 64;

    f32x4 accl[4][2], accr[4][2];
#pragma unroll
    for (int r = 0; r < 4; r++)
#pragma unroll
        for (int c = 0; c < 2; c++) {
            accl[r][c] = (f32x4){0.f, 0.f, 0.f, 0.f};
            accr[r][c] = (f32x4){0.f, 0.f, 0.f, 0.f};
        }

#pragma unroll
    for (int k0 = 0; k0 < FDIM; k0 += 32) {
        short8 a[4], bl[2], br[2];
#pragma unroll
        for (int r = 0; r < 4; r++) {
            int row = row0 + r * 16 + l16;
            if (row >= n) row = n - 1;
            a[r] = *(const short8*)(hb + (size_t)row * FDIM + k0 + quad * 8);
        }
#pragma unroll
        for (int c = 0; c < 2; c++) {
            size_t woff = (size_t)(c * 16 + l16) * FDIM + k0 + quad * 8;
            bl[c] = *(const short8*)(w2lt + woff);
            br[c] = *(const short8*)(w2rt + woff);
        }
#pragma unroll
        for (int r = 0; r < 4; r++)
#pragma unroll
            for (int c = 0; c < 2; c++) {
                accl[r][c] = __builtin_amdgcn_mfma_f32_16x16x32_bf16(a[r], bl[c], accl[r][c], 0, 0, 0);
                accr[r][c] = __builtin_amdgcn_mfma_f32_16x16x32_bf16(a[r], br[c], accr[r][c], 0, 0, 0);
            }
    }

#pragma unroll
    for (int r = 0; r < 4; r++)
#pragma unroll
        for (int reg = 0; reg < 4; reg++) {
            int row = row0 + r * 16 + quad * 4 + reg;
            if (row < n) {
#pragma unroll
                for (int c = 0; c < 2; c++) {
                    z2b[(size_t)row * CDIM + c * 16 + l16] = f2bf(accl[r][c][reg]);
                    r2 [(size_t)row * CDIM + c * 16 + l16] = accr[r][c][reg];
                }
            }
        }
}

// ---- combine2: out = inv_deg * sum_j z2b[j] + r2 + b2 ---------------------
// Wave per node; 4 edge-groups of 16 lanes; bf16 rows (64B) read as 1 uint/lane.

__global__ __launch_bounds__(256) void combine2_kernel(
        const uint_t* __restrict__ z2bu /* N x 16 uints */,
        const int* __restrict__ rowptr, const int* __restrict__ deg,
        const int* __restrict__ nbr, const float* __restrict__ inv_deg,
        const float* __restrict__ b2, const float* __restrict__ r2,
        float* __restrict__ out, int n) {
    int t = threadIdx.x;
    int i = blockIdx.x * 4 + (t >> 6);
    if (i >= n) return;
    int lane = t & 63;
    int g    = lane >> 4;
    int l16  = lane & 15;
    int start = rowptr[i];
    int d     = deg[i];
    float s0 = 0.f, s1 = 0.f;
    for (int e = g; e < d; e += 4) {
        int j = nbr[start + e];
        uint_t u = z2bu[(size_t)j * 16 + l16];
        s0 += bf2f_lo(u);
        s1 += bf2f_hi(u);
    }
    s0 += __shfl_xor(s0, 16, 64); s0 += __shfl_xor(s0, 32, 64);
    s1 += __shfl_xor(s1, 16, 64); s1 += __shfl_xor(s1, 32, 64);
    if (g == 0) {
        float inv = inv_deg[i];
        float2 rr = *(const float2*)(r2 + (size_t)i * CDIM + l16 * 2);
        float2 o;
        o.x = s0 * inv + rr.x + b2[l16 * 2];
        o.y = s1 * inv + rr.y + b2[l16 * 2 + 1];
        *(float2*)(out + (size_t)i * CDIM + l16 * 2) = o;
    }
}

// ---------------------------------------------------------------------------

extern "C" void kernel_launch(void* const* d_in, const int* in_sizes, int n_in,
                              void* d_out, int out_size, void* d_ws, size_t ws_size,
                              hipStream_t stream) {
    const float* x   = (const float*)d_in[0];
    const int*   ei  = (const int*)d_in[1];     // int64 in ref -> int32 here
    const float* W1l = (const float*)d_in[2];
    const float* b1  = (const float*)d_in[3];
    const float* W1r = (const float*)d_in[4];
    const float* W2l = (const float*)d_in[5];
    const float* b2  = (const float*)d_in[6];
    const float* W2r = (const float*)d_in[7];

    const int N = in_sizes[0] / FDIM;
    const int E = in_sizes[1] / 2;
    const int* src = ei;
    const int* dst = ei + E;

    char* p = (char*)d_ws;
    int*      deg      = (int*)p;      p += (size_t)N * sizeof(int);
    int*      cursor   = (int*)p;      p += (size_t)N * sizeof(int);
    int*      rowptr   = (int*)p;      p += (size_t)N * sizeof(int);
    float*    inv_deg  = (float*)p;    p += (size_t)N * sizeof(float);
    int*      partials = (int*)p;      p += 256 * sizeof(int);
    ushort_t* w1lt     = (ushort_t*)p; p += FDIM * FDIM * sizeof(ushort_t);
    ushort_t* w1rt     = (ushort_t*)p; p += FDIM * FDIM * sizeof(ushort_t);
    ushort_t* w2lt     = (ushort_t*)p; p += FDIM * CDIM * sizeof(ushort_t);
    ushort_t* w2rt     = (ushort_t*)p; p += FDIM * CDIM * sizeof(ushort_t);
    int*      nbr      = (int*)p;      p += (size_t)((E + 3) / 4 * 4) * sizeof(int);
    ushort_t* xb       = (ushort_t*)p; p += (size_t)N * FDIM * sizeof(ushort_t);
    ushort_t* aggb     = (ushort_t*)p; p += (size_t)N * FDIM * sizeof(ushort_t);
    ushort_t* hb       = (ushort_t*)p; p += (size_t)N * FDIM * sizeof(ushort_t);
    // z2b (6.4MB) + r2 (12.8MB) alias aggb (25.6MB): aggb dead after gemm1f.
    ushort_t* z2b      = aggb;
    float*    r2       = (float*)(aggb + (size_t)N * CDIM);

    const int SB = (N + SCAN_CHUNK - 1) / SCAN_CHUNK;
    const long long total8 = (long long)N * FDIM / 8;
    const int CB = (int)((total8 + 255) / 256);
    const int DB = (E + 255) / 256;

    hipMemsetAsync(deg, 0, 2 * (size_t)N * sizeof(int), stream);  // deg+cursor adjacent

    prep_kernel <<<CB + DB, 256, 0, stream>>>(x, (uint_t*)xb, total8, dst, deg, E, N, CB);
    scan1_kernel<<<SB, 256, 0, stream>>>(deg, partials, N);
    scan2_kernel<<<1, 256, 0, stream>>>(partials, SB);
    scan3_kernel<<<SB, 256, 0, stream>>>(deg, partials, rowptr, inv_deg, N);
    fill_kernel <<<DB, 256, 0, stream>>>(src, dst, rowptr, cursor, nbr, E, N);
    cvt_w_all_kernel<<<160, 256, 0, stream>>>(W1l, W1r, W2l, W2r, w1lt, w1rt, w2lt, w2rt);

    agg1_kernel  <<<(N + 3) / 4, 256, 0, stream>>>((const uint_t*)xb, rowptr, deg, nbr,
                                                   inv_deg, (uint_t*)aggb, N);
    gemm1f_kernel<<<(N + 63) / 64, 256, 0, stream>>>(xb, aggb, w1lt, w1rt, b1, hb, N);

    gemm2_kernel   <<<(N + 255) / 256, 256, 0, stream>>>(hb, w2lt, w2rt, z2b, r2, N);
    combine2_kernel<<<(N + 3) / 4, 256, 0, stream>>>((const uint_t*)z2b, rowptr, deg, nbr,
                                                     inv_deg, b2, r2, (float*)d_out, N);
}